// Round 8
// baseline (9506.400 us; speedup 1.0000x reference)
//
#include <hip/hip_runtime.h>
#include <hip/hip_bf16.h>

typedef unsigned int u32;
typedef unsigned short u16;
typedef u16 u16x8 __attribute__((ext_vector_type(8)));
typedef u32 u32x4 __attribute__((ext_vector_type(4)));

// ---------------------------------------------------------------------------
// B=32, N=64, DI=DO=R=256.  16 WGs x 512 threads, 2 batches per WG.
// Output: out_nodes [32,64,256] f32 (524288) then adj [32,64,64] f32.
//
// Workspace (floats): rep@0, pf@524288, ph@1048576, pq@1572864, po@2097152,
// panels (u16) @ float offset 2621440: 12 panels x 65536 bf16.
// Panel layout (coalesced): u16 element e:
//   j7=e&7, s=(e>>3)&63 (lane), r=(e>>9)&15 (instr), w=e>>13 (wave)
//   lp=s&15, lg=s>>4 -> k = lg*64 + r*4 + (j7>>1), c = w*32 + 2*lp + (j7&1).
// Lane l of wave w reads u16x8 at w*1024 + l + r*64 (1KB contiguous / instr).
//
// ROUND-7 LESSON: the persistent 128-VGPR cap came from DYNAMIC (extern)
// shared memory: compiler sees LDS=0, assumes multi-WG residency, targets
// 4 waves/SIMD -> 128-VGPR budget -> spills the weight stream. Static
// __shared__ of 157KB tells it 1 WG/CU (2 waves/SIMD) -> 256-VGPR budget
// (m214: 512-thr static-LDS kernels get 249 VGPRs, zero spill). Quarter
// rotation + sched_barrier fences retained; designed pressure ~110.
// ---------------------------------------------------------------------------

struct G4 { const float* Bm[4]; const float* bias[4]; float* C[4]; };

__global__ __launch_bounds__(256) void gemm16(const float* __restrict__ A, G4 g) {
  __shared__ float At[16 * 256];
  const int sub = blockIdx.y;
  const float* __restrict__ Bm = g.Bm[sub];
  const float* __restrict__ bias = g.bias[sub];
  float* __restrict__ C = g.C[sub];
  const int r0 = blockIdx.x * 16;
  const int t = threadIdx.x;
#pragma unroll
  for (int j = 0; j < 16; ++j) At[j * 256 + t] = A[(r0 + j) * 256 + t];
  __syncthreads();
  float acc[16];
#pragma unroll
  for (int j = 0; j < 16; ++j) acc[j] = 0.f;
  for (int k = 0; k < 256; ++k) {
    const float bv = Bm[k * 256 + t];
#pragma unroll
    for (int j = 0; j < 16; ++j) acc[j] = fmaf(At[j * 256 + k], bv, acc[j]);
  }
  const float bs = bias[t];
#pragma unroll
  for (int j = 0; j < 16; ++j) C[(r0 + j) * 256 + t] = acc[j] + bs;
}

struct C12 { const float* src[12]; };

__global__ __launch_bounds__(256) void cvt_panels(C12 c, u16* __restrict__ dst) {
  const int z = blockIdx.y;
  const float* __restrict__ in = c.src[z];
  const int e = blockIdx.x * 256 + threadIdx.x;
  const int j7 = e & 7, s = (e >> 3) & 63, r = (e >> 9) & 15, w = e >> 13;
  const int lp = s & 15, lg = s >> 4;
  const int k = lg * 64 + r * 4 + (j7 >> 1);
  const int col = w * 32 + 2 * lp + (j7 & 1);
  union { __hip_bfloat16 h; u16 u; } cv;
  cv.h = __float2bfloat16(in[k * 256 + col]);
  dst[z * 65536 + e] = cv.u;
}

// ---------------- main kernel helpers --------------------------------------
#define PID_F1 0
#define PID_F2 1
#define PID_F4 2
#define PID_H1 3
#define PID_H2 4
#define PID_H4 5
#define PID_Q1 6
#define PID_Q3 7
#define PID_O1 8
#define PID_O3 9
#define PID_SR 10
#define PID_SK 11

#define PSTRIDE 8192   // panel stride in u16x8 units

// LDS offsets (u32 units)
#define OFF_SREPT 0       // [256][68]  srepT2[c][n] packed bf16 A|B
#define OFF_SKEY  17408   // [64][292]  skey2[n][blk m:36][k&31]
#define OFF_H2    36096   // [2][288]   h packed, blocked [8][36]
#define OFF_Q2    36672   // [2][288]
#define OFF_XQR   37248   // [288]
#define OFF_XFH   37536   // [288]
#define OFF_XO    37824   // [288]
#define OFF_ATTW  38112   // [2][36]
#define OFF_LROW  38184   // float2[64]
#define OFF_HC    38312   // f32 [2 slots][2 batches][256]
#define LDS_U32   39336
#define LDS_BYTES (LDS_U32 * 4)

#define BAR() asm volatile("s_waitcnt lgkmcnt(0)\n\ts_barrier" ::: "memory")
#define SB()  __builtin_amdgcn_sched_barrier(0)

__device__ __forceinline__ u16 bfb(float x) {
  union { __hip_bfloat16 h; u16 u; } c; c.h = __float2bfloat16(x); return c.u;
}
__device__ __forceinline__ u32 pk2(float a, float b) {
  return (u32)bfb(a) | ((u32)bfb(b) << 16);
}
__device__ __forceinline__ float ulo(u32 x) { return __uint_as_float(x << 16); }
__device__ __forceinline__ float uhi(u32 x) { return __uint_as_float(x & 0xffff0000u); }
__device__ __forceinline__ float sgm(float x) { return 1.f / (1.f + __expf(-x)); }
__device__ __forceinline__ float tnh(float x) { return 1.f - 2.f / (__expf(2.f * x) + 1.f); }

__device__ __forceinline__ void ld4(u16x8 (&d)[4], const u16x8* __restrict__ s,
                                    int rbase) {
#pragma unroll
  for (int r = 0; r < 4; ++r) d[r] = s[(rbase + r) * 64];
}

// one quarter-item: 4 u16x8 weights (16 k x 2 cols) x 16 consecutive x-u32
// acc[0]=(c0,A) acc[1]=(c0,B) acc[2]=(c0+1,A) acc[3]=(c0+1,B)
__device__ __forceinline__ void fma_q(const u16x8 (&wr)[4], const u32* xb,
                                      float (&acc)[4]) {
#pragma unroll
  for (int q = 0; q < 4; ++q) {
    const u32x4 xv = *(const u32x4*)(xb + q * 4);
    const u16x8 wv = wr[q];
#pragma unroll
    for (int kk = 0; kk < 4; ++kk) {
      const u32 xw = xv[kk];
      const float xA = ulo(xw), xB = uhi(xw);
      const float w0 = __uint_as_float(((u32)wv[kk * 2]) << 16);
      const float w1 = __uint_as_float(((u32)wv[kk * 2 + 1]) << 16);
      acc[0] = fmaf(xA, w0, acc[0]);
      acc[1] = fmaf(xB, w0, acc[1]);
      acc[2] = fmaf(xA, w1, acc[2]);
      acc[3] = fmaf(xB, w1, acc[3]);
    }
  }
}

__device__ __forceinline__ void red4(float (&a)[4]) {
#pragma unroll
  for (int j = 0; j < 4; ++j) {
    a[j] += __shfl_xor(a[j], 16, 64);
    a[j] += __shfl_xor(a[j], 32, 64);
  }
}

__global__ __launch_bounds__(512) void dagsage_main(
    const float* __restrict__ adj,
    const float* __restrict__ b_srep, const float* __restrict__ b_skey,
    const float* __restrict__ pf, const float* __restrict__ ph,
    const float* __restrict__ pq, const float* __restrict__ po,
    const u16* __restrict__ panels,
    float* __restrict__ outp) {
  __shared__ u32 lds[LDS_U32];   // STATIC: lets compiler see 1 WG/CU
  const int t = threadIdx.x;
  const int w = t >> 6, l = t & 63;
  const int lp = l & 15, lg = l >> 4;
  const int c0 = w * 32 + 2 * lp;
  const int xoff = lg * 72;                 // 2 blocks of 36 per k-group
  const int bA = blockIdx.x * 2, bB = bA + 1;

  const u16x8* lane_pan = (const u16x8*)panels + w * 1024 + l;

  // ---- init: srepT2 / skey2 = biases (out_nodes == 0) ----
  for (int idx = t; idx < 17408; idx += 512) {
    const int c = idx / 68;
    lds[OFF_SREPT + idx] = pk2(b_srep[c], b_srep[c]);
  }
  for (int idx = t; idx < 18688; idx += 512) {
    const int rr = idx % 292;
    const int m = rr / 36, j = rr % 36;
    u32 v = 0;
    if (m < 8 && j < 32) { const int k = m * 32 + j; v = pk2(b_skey[k], b_skey[k]); }
    lds[OFF_SKEY + idx] = v;
  }
  __syncthreads();

  const float2 bs2 = *(const float2*)(b_srep + c0);
  const float2 bk2 = *(const float2*)(b_skey + c0);

  u16x8 A[4], B[4], C[4], D[4];
  float Fa[4], Ha[4], Qa[4], fr[4], fh[4];

// x-block shorthands (u32* into LDS)
#define XQR_  (lds + OFF_XQR + xoff)
#define XFH_  (lds + OFF_XFH + xoff)
#define XO_   (lds + OFF_XO + xoff)
#define XH_(p) (lds + OFF_H2 + (p) * 288 + xoff)
#define XQ_(p) (lds + OFF_Q2 + (p) * 288 + xoff)

// Uniform streaming item: consume quarters A,B,C,D of panel SELF against x
// block XP; refill D with SELF's last quarter, A,B,C with NEXT's first three.
// Quarter x-offsets within a lane's [2][36]-block region: 0, 16, 36, 52.
#define ITEM(XP, acc, SELF, NXT)                                              \
  fma_q(A, (XP), acc);      SB();                                             \
  ld4(D, lane_pan + (SELF) * PSTRIDE, 12); SB();                              \
  fma_q(B, (XP) + 16, acc); SB();                                             \
  ld4(A, lane_pan + (NXT) * PSTRIDE, 0);  SB();                               \
  fma_q(C, (XP) + 36, acc); SB();                                             \
  ld4(B, lane_pan + (NXT) * PSTRIDE, 4);  SB();                               \
  fma_q(D, (XP) + 52, acc); SB();                                             \
  ld4(C, lane_pan + (NXT) * PSTRIDE, 8);  SB();

  // prologue: preload F1 quarters 0..2
  ld4(A, lane_pan + PID_F1 * PSTRIDE, 0);
  ld4(B, lane_pan + PID_F1 * PSTRIDE, 4);
  ld4(C, lane_pan + PID_F1 * PSTRIDE, 8);

#pragma unroll 1
  for (int i = 0; i < 64; ++i) {
    const int rA = (bA * 64 + i) * 256 + c0;
    const int rB = (bB * 64 + i) * 256 + c0;

    // ================= Ph0: mask + it0 attention weights ==================
    float mk = 0.f;
    if (w < 2) {
      mk = adj[(((w == 0) ? bA : bB) * 64 + l) * 64 + i];
      float sm = mk;
#pragma unroll
      for (int o = 1; o < 64; o <<= 1) sm += __shfl_xor(sm, o, 64);
      ((u16*)(lds + OFF_ATTW + (l >> 5) * 36 + (l & 31)))[w] = bfb(mk / sm);
    }
    BAR();

// ---- qres phase (reads attw2 + srepT2, writes xqr2) ----
#define QRES_PHASE()                                                          \
  {                                                                           \
    float qr[4] = {0.f, 0.f, 0.f, 0.f};                                       \
    const u32* sp0 = lds + OFF_SREPT + c0 * 68 + lg * 16;                     \
    const u32* sp1 = sp0 + 68;                                                \
    const u32* ap = lds + OFF_ATTW + (lg >> 1) * 36 + (lg & 1) * 16;          \
    _Pragma("unroll")                                                         \
    for (int q = 0; q < 4; ++q) {                                             \
      const u32x4 av = *(const u32x4*)(ap + q * 4);                           \
      const u32x4 s0 = *(const u32x4*)(sp0 + q * 4);                          \
      const u32x4 s1 = *(const u32x4*)(sp1 + q * 4);                          \
      _Pragma("unroll")                                                       \
      for (int kk = 0; kk < 4; ++kk) {                                        \
        qr[0] = fmaf(ulo(av[kk]), ulo(s0[kk]), qr[0]);                        \
        qr[1] = fmaf(uhi(av[kk]), uhi(s0[kk]), qr[1]);                        \
        qr[2] = fmaf(ulo(av[kk]), ulo(s1[kk]), qr[2]);                        \
        qr[3] = fmaf(uhi(av[kk]), uhi(s1[kk]), qr[3]);                        \
      }                                                                       \
    }                                                                         \
    red4(qr);                                                                 \
    if (l < 16) {                                                             \
      lds[OFF_XQR + w * 36 + 2 * lp] = pk2(qr[0], qr[1]);                     \
      lds[OFF_XQR + w * 36 + 2 * lp + 1] = pk2(qr[2], qr[3]);                 \
    }                                                                         \
  }                                                                           \
  BAR();

    // ================= it0 =================
    QRES_PHASE();
    // P_FH0: F1(xqr)->Fa, H1(xqr)->Ha
    {
#pragma unroll
      for (int j = 0; j < 4; ++j) { Fa[j] = 0.f; Ha[j] = 0.f; }
      ITEM(XQR_, Fa, PID_F1, PID_H1);
      ITEM(XQR_, Ha, PID_H1, PID_Q1);
      red4(Fa); red4(Ha);
      if (l < 16) {
        const float2 pfA = *(const float2*)(pf + rA);
        const float2 pfB = *(const float2*)(pf + rB);
        const float2 phA = *(const float2*)(ph + rA);
        const float2 phB = *(const float2*)(ph + rB);
        fr[0] = sgm(Fa[0] + pfA.x); fr[1] = sgm(Fa[1] + pfB.x);
        fr[2] = sgm(Fa[2] + pfA.y); fr[3] = sgm(Fa[3] + pfB.y);
        const float h0 = (1.f - fr[0]) * tnh(Ha[0] + phA.x);
        const float h1 = (1.f - fr[1]) * tnh(Ha[1] + phB.x);
        const float h2_ = (1.f - fr[2]) * tnh(Ha[2] + phA.y);
        const float h3 = (1.f - fr[3]) * tnh(Ha[3] + phB.y);
        lds[OFF_H2 + w * 36 + 2 * lp] = pk2(h0, h1);
        lds[OFF_H2 + w * 36 + 2 * lp + 1] = pk2(h2_, h3);
        float* hc = (float*)(lds + OFF_HC);   // slot 0
        hc[c0] = h0; hc[c0 + 1] = h2_;
        hc[256 + c0] = h1; hc[256 + c0 + 1] = h3;
      }
      BAR();
    }
    // P_Q0: Q1(h0)->Qa
    {
#pragma unroll
      for (int j = 0; j < 4; ++j) Qa[j] = 0.f;
      ITEM(XH_(0), Qa, PID_Q1, PID_F1);   // load F1 for it1
      red4(Qa);
      if (l < 16) {
        const float2 pqA = *(const float2*)(pq + rA);
        const float2 pqB = *(const float2*)(pq + rB);
        lds[OFF_Q2 + w * 36 + 2 * lp] = pk2(Qa[0] + pqA.x, Qa[1] + pqB.x);
        lds[OFF_Q2 + w * 36 + 2 * lp + 1] = pk2(Qa[2] + pqA.y, Qa[3] + pqB.y);
      }
      BAR();
    }

// ================= full iteration macro (it1, it2) =================
// XN = panel loaded as NEXT of the last item (first item after this iter)
#define ITER_BODY(CP, NP, XN)                                                 \
  { /* logits */                                                              \
    const int nl = (w << 3) + (l >> 3), m = l & 7;                            \
    const u32* kp = lds + OFF_SKEY + nl * 292 + m * 36;                       \
    const u32* qp = lds + OFF_Q2 + (CP) * 288 + m * 36;                       \
    float la0 = 0.f, la1 = 0.f;                                               \
    _Pragma("unroll")                                                         \
    for (int q = 0; q < 8; ++q) {                                             \
      const u32x4 kv = *(const u32x4*)(kp + q * 4);                           \
      const u32x4 qv = *(const u32x4*)(qp + q * 4);                           \
      _Pragma("unroll")                                                       \
      for (int kk = 0; kk < 4; ++kk) {                                        \
        la0 = fmaf(ulo(qv[kk]), ulo(kv[kk]), la0);                            \
        la1 = fmaf(uhi(qv[kk]), uhi(kv[kk]), la1);                            \
      }                                                                       \
    }                                                                         \
    la0 += __shfl_xor(la0, 1, 64); la1 += __shfl_xor(la1, 1, 64);             \
    la0 += __shfl_xor(la0, 2, 64); la1 += __shfl_xor(la1, 2, 64);             \
    la0 += __shfl_xor(la0, 4, 64); la1 += __shfl_xor(la1, 4, 64);             \
    if (m == 0) *(float2*)(lds + OFF_LROW + nl * 2) = make_float2(la0, la1);  \
  }                                                                           \
  BAR();                                                                      \
  if (w < 2) { /* softmax */                                                  \
    const float2 lr = *(const float2*)(lds + OFF_LROW + l * 2);               \
    float v = (w == 0) ? lr.x : lr.y;                                         \
    float mx = v;                                                             \
    _Pragma("unroll")                                                         \
    for (int o = 1; o < 64; o <<= 1) mx = fmaxf(mx, __shfl_xor(mx, o, 64));   \
    const float e = __expf(v - mx) * mk;                                      \
    float ss = e;                                                             \
    _Pragma("unroll")                                                         \
    for (int o = 1; o < 64; o <<= 1) ss += __shfl_xor(ss, o, 64);             \
    ((u16*)(lds + OFF_ATTW + (l >> 5) * 36 + (l & 31)))[w] = bfb(e / ss);     \
  }                                                                           \
  BAR();                                                                      \
  QRES_PHASE();                                                               \
  { /* P4: F1,F2,F4 -> Fa ; H1,H4 -> Ha */                                    \
    _Pragma("unroll")                                                         \
    for (int j = 0; j < 4; ++j) { Fa[j] = 0.f; Ha[j] = 0.f; }                 \
    ITEM(XQR_, Fa, PID_F1, PID_F2);                                           \
    ITEM(XH_(CP), Fa, PID_F2, PID_F4);                                        \
    ITEM(XQ_(CP), Fa, PID_F4, PID_H1);                                        \
    ITEM(XQR_, Ha, PID_H1, PID_H4);                                           \
    ITEM(XQ_(CP), Ha, PID_H4, PID_H2);                                        \
    red4(Fa);                                                                 \
    if (l < 16) {                                                             \
      const float2 pfA_ = *(const float2*)(pf + rA);                          \
      const float2 pfB_ = *(const float2*)(pf + rB);                          \
      fr[0] = sgm(Fa[0] + pfA_.x); fr[1] = sgm(Fa[1] + pfB_.x);               \
      fr[2] = sgm(Fa[2] + pfA_.y); fr[3] = sgm(Fa[3] + pfB_.y);               \
      const float* hc = (const float*)(lds + OFF_HC + (CP) * 512);            \
      fh[0] = fr[0] * hc[c0]; fh[2] = fr[2] * hc[c0 + 1];                     \
      fh[1] = fr[1] * hc[256 + c0]; fh[3] = fr[3] * hc[256 + c0 + 1];         \
      lds[OFF_XFH + w * 36 + 2 * lp] = pk2(fh[0], fh[1]);                     \
      lds[OFF_XFH + w * 36 + 2 * lp + 1] = pk2(fh[2], fh[3]);                 \
    }                                                                         \
    BAR();                                                                    \
  }                                                                           \
  { /* P5: H2(xfh) -> Ha ; Q3(q) -> Qa */                                     \
    _Pragma("unroll")                                                         \
    for (int j = 0; j < 4; ++j) Qa[j] = 0.f;                                  \
    ITEM(XFH_, Ha, PID_H2, PID_Q3);                                           \
    ITEM(XQ_(CP), Qa, PID_Q3, PID_Q1);                                        \
    red4(Ha);                                                                 \
    if (l < 16) {                                                             \
      const float2 phA_ = *(const float2*)(ph + rA);                          \
      const float2 phB_ = *(const float2*)(ph + rB);                          \
      const float h0 = fh[0] + (1.f - fr[0]) * tnh(Ha[0] + phA_.x);           \
      const float h1 = fh[1] + (1.f - fr[1]) * tnh(Ha[1] + phB_.x);           \
      const float h2_ = fh[2] + (1.f - fr[2]) * tnh(Ha[2] + phA_.y);          \
      const float h3 = fh[3] + (1.f - fr[3]) * tnh(Ha[3] + phB_.y);           \
      lds[OFF_H2 + (NP) * 288 + w * 36 + 2 * lp] = pk2(h0, h1);               \
      lds[OFF_H2 + (NP) * 288 + w * 36 + 2 * lp + 1] = pk2(h2_, h3);          \
      float* hcn = (float*)(lds + OFF_HC + (NP) * 512);                       \
      hcn[c0] = h0; hcn[c0 + 1] = h2_;                                        \
      hcn[256 + c0] = h1; hcn[256 + c0 + 1] = h3;                             \
    }                                                                         \
    BAR();                                                                    \
  }                                                                           \
  { /* P6: Q1(h') -> Qa */                                                    \
    ITEM(XH_(NP), Qa, PID_Q1, XN);                                            \
    red4(Qa);                                                                 \
    if (l < 16) {                                                             \
      const float2 pqA_ = *(const float2*)(pq + rA);                          \
      const float2 pqB_ = *(const float2*)(pq + rB);                          \
      lds[OFF_Q2 + (NP) * 288 + w * 36 + 2 * lp] =                            \
          pk2(Qa[0] + pqA_.x, Qa[1] + pqB_.x);                                \
      lds[OFF_Q2 + (NP) * 288 + w * 36 + 2 * lp + 1] =                        \
          pk2(Qa[2] + pqA_.y, Qa[3] + pqB_.y);                                \
    }                                                                         \
    BAR();                                                                    \
  }

    ITER_BODY(0, 1, PID_F1);   // it1
    ITER_BODY(1, 0, PID_O1);   // it2

    // ================= P7: out_i = O1.h + O3.q + po =================
    {
      float Oa[4] = {0.f, 0.f, 0.f, 0.f};
      ITEM(XH_(0), Oa, PID_O1, PID_O3);
      ITEM(XQ_(0), Oa, PID_O3, PID_SR);
      red4(Oa);
      if (l < 16) {
        const float2 poA = *(const float2*)(po + rA);
        const float2 poB = *(const float2*)(po + rB);
        const float o0 = Oa[0] + poA.x, o1 = Oa[1] + poB.x;
        const float o2 = Oa[2] + poA.y, o3 = Oa[3] + poB.y;
        *(float2*)(outp + rA) = make_float2(o0, o2);
        *(float2*)(outp + rB) = make_float2(o1, o3);
        lds[OFF_XO + w * 36 + 2 * lp] = pk2(o0, o1);
        lds[OFF_XO + w * 36 + 2 * lp + 1] = pk2(o2, o3);
      }
      BAR();
    }
    // ================= P8: srep/skey incremental row update ===============
    {
      float Ra[4] = {0.f, 0.f, 0.f, 0.f}, Ka[4] = {0.f, 0.f, 0.f, 0.f};
      ITEM(XO_, Ra, PID_SR, PID_SK);
      ITEM(XO_, Ka, PID_SK, PID_F1);     // F1 for next step
      red4(Ra); red4(Ka);
      if (l < 16) {
        lds[OFF_SREPT + c0 * 68 + i] = pk2(Ra[0] + bs2.x, Ra[1] + bs2.x);
        lds[OFF_SREPT + (c0 + 1) * 68 + i] = pk2(Ra[2] + bs2.y, Ra[3] + bs2.y);
        lds[OFF_SKEY + i * 292 + w * 36 + 2 * lp] =
            pk2(Ka[0] + bk2.x, Ka[1] + bk2.x);
        lds[OFF_SKEY + i * 292 + w * 36 + 2 * lp + 1] =
            pk2(Ka[2] + bk2.y, Ka[3] + bk2.y);
      }
      BAR();
    }
  }
}

// ---------------------------------------------------------------------------
extern "C" void kernel_launch(void* const* d_in, const int* in_sizes, int n_in,
                              void* d_out, int out_size, void* d_ws, size_t ws_size,
                              hipStream_t stream) {
  const float* nodes    = (const float*)d_in[0];
  const float* adj      = (const float*)d_in[1];
  const float* W_self   = (const float*)d_in[2];
  const float* b_self   = (const float*)d_in[3];
  const float* W_srep   = (const float*)d_in[4];
  const float* b_srep   = (const float*)d_in[5];
  const float* W_skey   = (const float*)d_in[6];
  const float* b_skey   = (const float*)d_in[7];
  const float* W_forget = (const float*)d_in[8];
  const float* b_forget = (const float*)d_in[9];
  const float* W_hid    = (const float*)d_in[10];
  const float* b_hid    = (const float*)d_in[11];
  const float* W_query  = (const float*)d_in[12];
  const float* b_query  = (const float*)d_in[13];
  const float* W_out    = (const float*)d_in[14];
  const float* b_out    = (const float*)d_in[15];
  float* out = (float*)d_out;

  float* rep = (float*)d_ws;
  float* pf = rep + 524288;
  float* ph = pf + 524288;
  float* pq = ph + 524288;
  float* po = pq + 524288;
  u16* panels = (u16*)(po + 524288);

  hipMemcpyAsync(out + 524288, adj, 131072 * sizeof(float),
                 hipMemcpyDeviceToDevice, stream);

  C12 ca;
  ca.src[0]  = W_forget;             // F1  (rows 0:256   <- query_res)
  ca.src[1]  = W_forget + 256 * 256; // F2  (rows 256:512 <- hidden)
  ca.src[2]  = W_forget + 768 * 256; // F4  (rows 768:1024<- query)
  ca.src[3]  = W_hid;                // H1
  ca.src[4]  = W_hid + 256 * 256;    // H2  (<- forget*hidden)
  ca.src[5]  = W_hid + 768 * 256;    // H4
  ca.src[6]  = W_query;              // Q1  (rows 0:256 <- hidden)
  ca.src[7]  = W_query + 512 * 256;  // Q3  (rows 512:768 <- query)
  ca.src[8]  = W_out;                // O1
  ca.src[9]  = W_out + 512 * 256;    // O3
  ca.src[10] = W_srep;               // SR
  ca.src[11] = W_skey;               // SK
  cvt_panels<<<dim3(256, 12), 256, 0, stream>>>(ca, panels);

  G4 g1;
  for (int j = 0; j < 4; ++j) { g1.Bm[j] = W_self; g1.bias[j] = b_self; g1.C[j] = rep; }
  gemm16<<<dim3(128, 1), 256, 0, stream>>>(nodes, g1);

  G4 g2;
  g2.Bm[0] = W_forget + 512 * 256; g2.bias[0] = b_forget; g2.C[0] = pf;
  g2.Bm[1] = W_hid + 512 * 256;    g2.bias[1] = b_hid;    g2.C[1] = ph;
  g2.Bm[2] = W_query + 256 * 256;  g2.bias[2] = b_query;  g2.C[2] = pq;
  g2.Bm[3] = W_out + 256 * 256;    g2.bias[3] = b_out;    g2.C[3] = po;
  gemm16<<<dim3(128, 4), 256, 0, stream>>>(rep, g2);

  dagsage_main<<<16, 512, 0, stream>>>(adj, b_srep, b_skey,
                                       pf, ph, pq, po, panels, out);
}

// Round 9
// 8588.105 us; speedup vs baseline: 1.1069x; 1.1069x over previous
//
#include <hip/hip_runtime.h>
#include <hip/hip_bf16.h>

typedef unsigned int u32;
typedef unsigned short u16;
typedef u16 u16x8 __attribute__((ext_vector_type(8)));
typedef u32 u32x4 __attribute__((ext_vector_type(4)));

// ---------------------------------------------------------------------------
// B=32, N=64, DI=DO=R=256.  16 WGs x 512 threads, 2 batches per WG.
// Output: out_nodes [32,64,256] f32 (524288) then adj [32,64,64] f32.
//
// Workspace (floats): rep@0, pf@524288, ph@1048576, pq@1572864, po@2097152,
// panels (u16) @ float offset 2621440: 12 panels x 65536 bf16.
// Panel layout (coalesced): u16 element e:
//   j7=e&7, s=(e>>3)&63 (lane), r=(e>>9)&15 (instr), w=e>>13 (wave)
//   lp=s&15, lg=s>>4 -> k = lg*64 + r*4 + (j7>>1), c = w*32 + 2*lp + (j7&1).
// Lane l of wave w reads u16x8 at w*1024 + l + r*64 (1KB contiguous / instr).
//
// ROUND-8 LESSON: no compiler knob moves the 128-VGPR budget for this kernel
// (launch_bounds min-waves, waves_per_eu, static LDS all tried: VGPR=128,
// ~278MB scratch writebacks). So fit UNDER 128 by design: two quarter
// buffers A,B (32 VGPRs), lookahead 1 quarter, sched_barrier-pinned order.
// Designed pressure ~90 -> real slack -> zero spill.
// ---------------------------------------------------------------------------

struct G4 { const float* Bm[4]; const float* bias[4]; float* C[4]; };

__global__ __launch_bounds__(256) void gemm16(const float* __restrict__ A, G4 g) {
  __shared__ float At[16 * 256];
  const int sub = blockIdx.y;
  const float* __restrict__ Bm = g.Bm[sub];
  const float* __restrict__ bias = g.bias[sub];
  float* __restrict__ C = g.C[sub];
  const int r0 = blockIdx.x * 16;
  const int t = threadIdx.x;
#pragma unroll
  for (int j = 0; j < 16; ++j) At[j * 256 + t] = A[(r0 + j) * 256 + t];
  __syncthreads();
  float acc[16];
#pragma unroll
  for (int j = 0; j < 16; ++j) acc[j] = 0.f;
  for (int k = 0; k < 256; ++k) {
    const float bv = Bm[k * 256 + t];
#pragma unroll
    for (int j = 0; j < 16; ++j) acc[j] = fmaf(At[j * 256 + k], bv, acc[j]);
  }
  const float bs = bias[t];
#pragma unroll
  for (int j = 0; j < 16; ++j) C[(r0 + j) * 256 + t] = acc[j] + bs;
}

struct C12 { const float* src[12]; };

__global__ __launch_bounds__(256) void cvt_panels(C12 c, u16* __restrict__ dst) {
  const int z = blockIdx.y;
  const float* __restrict__ in = c.src[z];
  const int e = blockIdx.x * 256 + threadIdx.x;
  const int j7 = e & 7, s = (e >> 3) & 63, r = (e >> 9) & 15, w = e >> 13;
  const int lp = s & 15, lg = s >> 4;
  const int k = lg * 64 + r * 4 + (j7 >> 1);
  const int col = w * 32 + 2 * lp + (j7 & 1);
  union { __hip_bfloat16 h; u16 u; } cv;
  cv.h = __float2bfloat16(in[k * 256 + col]);
  dst[z * 65536 + e] = cv.u;
}

// ---------------- main kernel helpers --------------------------------------
#define PID_F1 0
#define PID_F2 1
#define PID_F4 2
#define PID_H1 3
#define PID_H2 4
#define PID_H4 5
#define PID_Q1 6
#define PID_Q3 7
#define PID_O1 8
#define PID_O3 9
#define PID_SR 10
#define PID_SK 11

#define PSTRIDE 8192   // panel stride in u16x8 units

// LDS offsets (u32 units)
#define OFF_SREPT 0       // [256][68]  srepT2[c][n] packed bf16 A|B
#define OFF_SKEY  17408   // [64][292]  skey2[n][blk m:36][k&31]
#define OFF_H2    36096   // [2][288]   h packed, blocked [8][36]
#define OFF_Q2    36672   // [2][288]
#define OFF_XQR   37248   // [288]
#define OFF_XFH   37536   // [288]
#define OFF_XO    37824   // [288]
#define OFF_ATTW  38112   // [2][36]
#define OFF_LROW  38184   // float2[64]
#define OFF_HC    38312   // f32 [2 slots][2 batches][256]
#define LDS_U32   39336
#define LDS_BYTES (LDS_U32 * 4)

#define BAR() asm volatile("s_waitcnt lgkmcnt(0)\n\ts_barrier" ::: "memory")
#define SB()  __builtin_amdgcn_sched_barrier(0)

__device__ __forceinline__ u16 bfb(float x) {
  union { __hip_bfloat16 h; u16 u; } c; c.h = __float2bfloat16(x); return c.u;
}
__device__ __forceinline__ u32 pk2(float a, float b) {
  return (u32)bfb(a) | ((u32)bfb(b) << 16);
}
__device__ __forceinline__ float ulo(u32 x) { return __uint_as_float(x << 16); }
__device__ __forceinline__ float uhi(u32 x) { return __uint_as_float(x & 0xffff0000u); }
__device__ __forceinline__ float sgm(float x) { return 1.f / (1.f + __expf(-x)); }
__device__ __forceinline__ float tnh(float x) { return 1.f - 2.f / (__expf(2.f * x) + 1.f); }

__device__ __forceinline__ void ld4(u16x8 (&d)[4], const u16x8* __restrict__ s,
                                    int rbase) {
#pragma unroll
  for (int r = 0; r < 4; ++r) d[r] = s[(rbase + r) * 64];
}

// one quarter-item: 4 u16x8 weights (16 k x 2 cols) x 16 consecutive x-u32
// acc[0]=(c0,A) acc[1]=(c0,B) acc[2]=(c0+1,A) acc[3]=(c0+1,B)
__device__ __forceinline__ void fma_q(const u16x8 (&wr)[4], const u32* xb,
                                      float (&acc)[4]) {
#pragma unroll
  for (int q = 0; q < 4; ++q) {
    const u32x4 xv = *(const u32x4*)(xb + q * 4);
    const u16x8 wv = wr[q];
#pragma unroll
    for (int kk = 0; kk < 4; ++kk) {
      const u32 xw = xv[kk];
      const float xA = ulo(xw), xB = uhi(xw);
      const float w0 = __uint_as_float(((u32)wv[kk * 2]) << 16);
      const float w1 = __uint_as_float(((u32)wv[kk * 2 + 1]) << 16);
      acc[0] = fmaf(xA, w0, acc[0]);
      acc[1] = fmaf(xB, w0, acc[1]);
      acc[2] = fmaf(xA, w1, acc[2]);
      acc[3] = fmaf(xB, w1, acc[3]);
    }
  }
}

__device__ __forceinline__ void red4(float (&a)[4]) {
#pragma unroll
  for (int j = 0; j < 4; ++j) {
    a[j] += __shfl_xor(a[j], 16, 64);
    a[j] += __shfl_xor(a[j], 32, 64);
  }
}

__global__ __launch_bounds__(512) void dagsage_main(
    const float* __restrict__ adj,
    const float* __restrict__ b_srep, const float* __restrict__ b_skey,
    const float* __restrict__ pf, const float* __restrict__ ph,
    const float* __restrict__ pq, const float* __restrict__ po,
    const u16* __restrict__ panels,
    float* __restrict__ outp) {
  __shared__ u32 lds[LDS_U32];
  const int t = threadIdx.x;
  const int w = t >> 6, l = t & 63;
  const int lp = l & 15, lg = l >> 4;
  const int c0 = w * 32 + 2 * lp;
  const int xoff = lg * 72;                 // 2 blocks of 36 per k-group
  const int bA = blockIdx.x * 2, bB = bA + 1;

  const u16x8* lane_pan = (const u16x8*)panels + w * 1024 + l;

  // ---- init: srepT2 / skey2 = biases (out_nodes == 0) ----
  for (int idx = t; idx < 17408; idx += 512) {
    const int c = idx / 68;
    lds[OFF_SREPT + idx] = pk2(b_srep[c], b_srep[c]);
  }
  for (int idx = t; idx < 18688; idx += 512) {
    const int rr = idx % 292;
    const int m = rr / 36, j = rr % 36;
    u32 v = 0;
    if (m < 8 && j < 32) { const int k = m * 32 + j; v = pk2(b_skey[k], b_skey[k]); }
    lds[OFF_SKEY + idx] = v;
  }
  __syncthreads();

  const float2 bs2 = *(const float2*)(b_srep + c0);
  const float2 bk2 = *(const float2*)(b_skey + c0);

  u16x8 A[4], B[4];                       // 32 VGPRs of weight stream
  float Fa[4], Ha[4], Qa[4], fr[4], fh[4];

// x-block shorthands (u32* into LDS)
#define XQR_  (lds + OFF_XQR + xoff)
#define XFH_  (lds + OFF_XFH + xoff)
#define XO_   (lds + OFF_XO + xoff)
#define XH_(p) (lds + OFF_H2 + (p) * 288 + xoff)
#define XQ_(p) (lds + OFF_Q2 + (p) * 288 + xoff)

// Entry invariant: A holds SELF's quarter 0. Lookahead = 1 quarter:
// issue the load of quarter n+1 into the free buffer, then fma quarter n.
// Exit: A holds NXT's quarter 0.
#define ITEM(XP, acc, SELF, NXT)                                              \
  ld4(B, lane_pan + (SELF) * PSTRIDE, 4);  SB();                              \
  fma_q(A, (XP), acc);                     SB();                              \
  ld4(A, lane_pan + (SELF) * PSTRIDE, 8);  SB();                              \
  fma_q(B, (XP) + 16, acc);                SB();                              \
  ld4(B, lane_pan + (SELF) * PSTRIDE, 12); SB();                              \
  fma_q(A, (XP) + 36, acc);                SB();                              \
  ld4(A, lane_pan + (NXT) * PSTRIDE, 0);   SB();                              \
  fma_q(B, (XP) + 52, acc);                SB();

  // prologue: preload F1 quarter 0
  ld4(A, lane_pan + PID_F1 * PSTRIDE, 0);

#pragma unroll 1
  for (int i = 0; i < 64; ++i) {
    const int rA = (bA * 64 + i) * 256 + c0;
    const int rB = (bB * 64 + i) * 256 + c0;

    // ================= Ph0: mask + it0 attention weights ==================
    float mk = 0.f;
    if (w < 2) {
      mk = adj[(((w == 0) ? bA : bB) * 64 + l) * 64 + i];
      float sm = mk;
#pragma unroll
      for (int o = 1; o < 64; o <<= 1) sm += __shfl_xor(sm, o, 64);
      ((u16*)(lds + OFF_ATTW + (l >> 5) * 36 + (l & 31)))[w] = bfb(mk / sm);
    }
    BAR();

// ---- qres phase (reads attw2 + srepT2, writes xqr2) ----
#define QRES_PHASE()                                                          \
  {                                                                           \
    float qr[4] = {0.f, 0.f, 0.f, 0.f};                                       \
    const u32* sp0 = lds + OFF_SREPT + c0 * 68 + lg * 16;                     \
    const u32* sp1 = sp0 + 68;                                                \
    const u32* ap = lds + OFF_ATTW + (lg >> 1) * 36 + (lg & 1) * 16;          \
    _Pragma("unroll")                                                         \
    for (int q = 0; q < 4; ++q) {                                             \
      const u32x4 av = *(const u32x4*)(ap + q * 4);                           \
      const u32x4 s0 = *(const u32x4*)(sp0 + q * 4);                          \
      const u32x4 s1 = *(const u32x4*)(sp1 + q * 4);                          \
      _Pragma("unroll")                                                       \
      for (int kk = 0; kk < 4; ++kk) {                                        \
        qr[0] = fmaf(ulo(av[kk]), ulo(s0[kk]), qr[0]);                        \
        qr[1] = fmaf(uhi(av[kk]), uhi(s0[kk]), qr[1]);                        \
        qr[2] = fmaf(ulo(av[kk]), ulo(s1[kk]), qr[2]);                        \
        qr[3] = fmaf(uhi(av[kk]), uhi(s1[kk]), qr[3]);                        \
      }                                                                       \
    }                                                                         \
    red4(qr);                                                                 \
    if (l < 16) {                                                             \
      lds[OFF_XQR + w * 36 + 2 * lp] = pk2(qr[0], qr[1]);                     \
      lds[OFF_XQR + w * 36 + 2 * lp + 1] = pk2(qr[2], qr[3]);                 \
    }                                                                         \
  }                                                                           \
  BAR();

    // ================= it0 =================
    QRES_PHASE();
    // P_FH0: F1(xqr)->Fa, H1(xqr)->Ha
    {
#pragma unroll
      for (int j = 0; j < 4; ++j) { Fa[j] = 0.f; Ha[j] = 0.f; }
      ITEM(XQR_, Fa, PID_F1, PID_H1);
      ITEM(XQR_, Ha, PID_H1, PID_Q1);
      red4(Fa); red4(Ha);
      if (l < 16) {
        const float2 pfA = *(const float2*)(pf + rA);
        const float2 pfB = *(const float2*)(pf + rB);
        const float2 phA = *(const float2*)(ph + rA);
        const float2 phB = *(const float2*)(ph + rB);
        fr[0] = sgm(Fa[0] + pfA.x); fr[1] = sgm(Fa[1] + pfB.x);
        fr[2] = sgm(Fa[2] + pfA.y); fr[3] = sgm(Fa[3] + pfB.y);
        const float h0 = (1.f - fr[0]) * tnh(Ha[0] + phA.x);
        const float h1 = (1.f - fr[1]) * tnh(Ha[1] + phB.x);
        const float h2_ = (1.f - fr[2]) * tnh(Ha[2] + phA.y);
        const float h3 = (1.f - fr[3]) * tnh(Ha[3] + phB.y);
        lds[OFF_H2 + w * 36 + 2 * lp] = pk2(h0, h1);
        lds[OFF_H2 + w * 36 + 2 * lp + 1] = pk2(h2_, h3);
        float* hc = (float*)(lds + OFF_HC);   // slot 0
        hc[c0] = h0; hc[c0 + 1] = h2_;
        hc[256 + c0] = h1; hc[256 + c0 + 1] = h3;
      }
      BAR();
    }
    // P_Q0: Q1(h0)->Qa
    {
#pragma unroll
      for (int j = 0; j < 4; ++j) Qa[j] = 0.f;
      ITEM(XH_(0), Qa, PID_Q1, PID_F1);   // load F1 for it1
      red4(Qa);
      if (l < 16) {
        const float2 pqA = *(const float2*)(pq + rA);
        const float2 pqB = *(const float2*)(pq + rB);
        lds[OFF_Q2 + w * 36 + 2 * lp] = pk2(Qa[0] + pqA.x, Qa[1] + pqB.x);
        lds[OFF_Q2 + w * 36 + 2 * lp + 1] = pk2(Qa[2] + pqA.y, Qa[3] + pqB.y);
      }
      BAR();
    }

// ================= full iteration macro (it1, it2) =================
// XN = panel loaded as NEXT of the last item (first item after this iter)
#define ITER_BODY(CP, NP, XN)                                                 \
  { /* logits */                                                              \
    const int nl = (w << 3) + (l >> 3), m = l & 7;                            \
    const u32* kp = lds + OFF_SKEY + nl * 292 + m * 36;                       \
    const u32* qp = lds + OFF_Q2 + (CP) * 288 + m * 36;                       \
    float la0 = 0.f, la1 = 0.f;                                               \
    _Pragma("unroll")                                                         \
    for (int q = 0; q < 8; ++q) {                                             \
      const u32x4 kv = *(const u32x4*)(kp + q * 4);                           \
      const u32x4 qv = *(const u32x4*)(qp + q * 4);                           \
      _Pragma("unroll")                                                       \
      for (int kk = 0; kk < 4; ++kk) {                                        \
        la0 = fmaf(ulo(qv[kk]), ulo(kv[kk]), la0);                            \
        la1 = fmaf(uhi(qv[kk]), uhi(kv[kk]), la1);                            \
      }                                                                       \
    }                                                                         \
    la0 += __shfl_xor(la0, 1, 64); la1 += __shfl_xor(la1, 1, 64);             \
    la0 += __shfl_xor(la0, 2, 64); la1 += __shfl_xor(la1, 2, 64);             \
    la0 += __shfl_xor(la0, 4, 64); la1 += __shfl_xor(la1, 4, 64);             \
    if (m == 0) *(float2*)(lds + OFF_LROW + nl * 2) = make_float2(la0, la1);  \
  }                                                                           \
  BAR();                                                                      \
  if (w < 2) { /* softmax */                                                  \
    const float2 lr = *(const float2*)(lds + OFF_LROW + l * 2);               \
    float v = (w == 0) ? lr.x : lr.y;                                         \
    float mx = v;                                                             \
    _Pragma("unroll")                                                         \
    for (int o = 1; o < 64; o <<= 1) mx = fmaxf(mx, __shfl_xor(mx, o, 64));   \
    const float e = __expf(v - mx) * mk;                                      \
    float ss = e;                                                             \
    _Pragma("unroll")                                                         \
    for (int o = 1; o < 64; o <<= 1) ss += __shfl_xor(ss, o, 64);             \
    ((u16*)(lds + OFF_ATTW + (l >> 5) * 36 + (l & 31)))[w] = bfb(e / ss);     \
  }                                                                           \
  BAR();                                                                      \
  QRES_PHASE();                                                               \
  { /* P4: F1,F2,F4 -> Fa ; H1,H4 -> Ha */                                    \
    _Pragma("unroll")                                                         \
    for (int j = 0; j < 4; ++j) { Fa[j] = 0.f; Ha[j] = 0.f; }                 \
    ITEM(XQR_, Fa, PID_F1, PID_F2);                                           \
    ITEM(XH_(CP), Fa, PID_F2, PID_F4);                                        \
    ITEM(XQ_(CP), Fa, PID_F4, PID_H1);                                        \
    ITEM(XQR_, Ha, PID_H1, PID_H4);                                           \
    ITEM(XQ_(CP), Ha, PID_H4, PID_H2);                                        \
    red4(Fa);                                                                 \
    if (l < 16) {                                                             \
      const float2 pfA_ = *(const float2*)(pf + rA);                          \
      const float2 pfB_ = *(const float2*)(pf + rB);                          \
      fr[0] = sgm(Fa[0] + pfA_.x); fr[1] = sgm(Fa[1] + pfB_.x);               \
      fr[2] = sgm(Fa[2] + pfA_.y); fr[3] = sgm(Fa[3] + pfB_.y);               \
      const float* hc = (const float*)(lds + OFF_HC + (CP) * 512);            \
      fh[0] = fr[0] * hc[c0]; fh[2] = fr[2] * hc[c0 + 1];                     \
      fh[1] = fr[1] * hc[256 + c0]; fh[3] = fr[3] * hc[256 + c0 + 1];         \
      lds[OFF_XFH + w * 36 + 2 * lp] = pk2(fh[0], fh[1]);                     \
      lds[OFF_XFH + w * 36 + 2 * lp + 1] = pk2(fh[2], fh[3]);                 \
    }                                                                         \
    BAR();                                                                    \
  }                                                                           \
  { /* P5: H2(xfh) -> Ha ; Q3(q) -> Qa */                                     \
    _Pragma("unroll")                                                         \
    for (int j = 0; j < 4; ++j) Qa[j] = 0.f;                                  \
    ITEM(XFH_, Ha, PID_H2, PID_Q3);                                           \
    ITEM(XQ_(CP), Qa, PID_Q3, PID_Q1);                                        \
    red4(Ha);                                                                 \
    if (l < 16) {                                                             \
      const float2 phA_ = *(const float2*)(ph + rA);                          \
      const float2 phB_ = *(const float2*)(ph + rB);                          \
      const float h0 = fh[0] + (1.f - fr[0]) * tnh(Ha[0] + phA_.x);           \
      const float h1 = fh[1] + (1.f - fr[1]) * tnh(Ha[1] + phB_.x);           \
      const float h2_ = fh[2] + (1.f - fr[2]) * tnh(Ha[2] + phA_.y);          \
      const float h3 = fh[3] + (1.f - fr[3]) * tnh(Ha[3] + phB_.y);           \
      lds[OFF_H2 + (NP) * 288 + w * 36 + 2 * lp] = pk2(h0, h1);               \
      lds[OFF_H2 + (NP) * 288 + w * 36 + 2 * lp + 1] = pk2(h2_, h3);          \
      float* hcn = (float*)(lds + OFF_HC + (NP) * 512);                       \
      hcn[c0] = h0; hcn[c0 + 1] = h2_;                                        \
      hcn[256 + c0] = h1; hcn[256 + c0 + 1] = h3;                             \
    }                                                                         \
    BAR();                                                                    \
  }                                                                           \
  { /* P6: Q1(h') -> Qa */                                                    \
    ITEM(XH_(NP), Qa, PID_Q1, XN);                                            \
    red4(Qa);                                                                 \
    if (l < 16) {                                                             \
      const float2 pqA_ = *(const float2*)(pq + rA);                          \
      const float2 pqB_ = *(const float2*)(pq + rB);                          \
      lds[OFF_Q2 + (NP) * 288 + w * 36 + 2 * lp] =                            \
          pk2(Qa[0] + pqA_.x, Qa[1] + pqB_.x);                                \
      lds[OFF_Q2 + (NP) * 288 + w * 36 + 2 * lp + 1] =                        \
          pk2(Qa[2] + pqA_.y, Qa[3] + pqB_.y);                                \
    }                                                                         \
    BAR();                                                                    \
  }

    ITER_BODY(0, 1, PID_F1);   // it1
    ITER_BODY(1, 0, PID_O1);   // it2

    // ================= P7: out_i = O1.h + O3.q + po =================
    {
      float Oa[4] = {0.f, 0.f, 0.f, 0.f};
      ITEM(XH_(0), Oa, PID_O1, PID_O3);
      ITEM(XQ_(0), Oa, PID_O3, PID_SR);
      red4(Oa);
      if (l < 16) {
        const float2 poA = *(const float2*)(po + rA);
        const float2 poB = *(const float2*)(po + rB);
        const float o0 = Oa[0] + poA.x, o1 = Oa[1] + poB.x;
        const float o2 = Oa[2] + poA.y, o3 = Oa[3] + poB.y;
        *(float2*)(outp + rA) = make_float2(o0, o2);
        *(float2*)(outp + rB) = make_float2(o1, o3);
        lds[OFF_XO + w * 36 + 2 * lp] = pk2(o0, o1);
        lds[OFF_XO + w * 36 + 2 * lp + 1] = pk2(o2, o3);
      }
      BAR();
    }
    // ================= P8: srep/skey incremental row update ===============
    {
      float Ra[4] = {0.f, 0.f, 0.f, 0.f}, Ka[4] = {0.f, 0.f, 0.f, 0.f};
      ITEM(XO_, Ra, PID_SR, PID_SK);
      ITEM(XO_, Ka, PID_SK, PID_F1);     // F1 for next step
      red4(Ra); red4(Ka);
      if (l < 16) {
        lds[OFF_SREPT + c0 * 68 + i] = pk2(Ra[0] + bs2.x, Ra[1] + bs2.x);
        lds[OFF_SREPT + (c0 + 1) * 68 + i] = pk2(Ra[2] + bs2.y, Ra[3] + bs2.y);
        lds[OFF_SKEY + i * 292 + w * 36 + 2 * lp] =
            pk2(Ka[0] + bk2.x, Ka[1] + bk2.x);
        lds[OFF_SKEY + i * 292 + w * 36 + 2 * lp + 1] =
            pk2(Ka[2] + bk2.y, Ka[3] + bk2.y);
      }
      BAR();
    }
  }
}

// ---------------------------------------------------------------------------
extern "C" void kernel_launch(void* const* d_in, const int* in_sizes, int n_in,
                              void* d_out, int out_size, void* d_ws, size_t ws_size,
                              hipStream_t stream) {
  const float* nodes    = (const float*)d_in[0];
  const float* adj      = (const float*)d_in[1];
  const float* W_self   = (const float*)d_in[2];
  const float* b_self   = (const float*)d_in[3];
  const float* W_srep   = (const float*)d_in[4];
  const float* b_srep   = (const float*)d_in[5];
  const float* W_skey   = (const float*)d_in[6];
  const float* b_skey   = (const float*)d_in[7];
  const float* W_forget = (const float*)d_in[8];
  const float* b_forget = (const float*)d_in[9];
  const float* W_hid    = (const float*)d_in[10];
  const float* b_hid    = (const float*)d_in[11];
  const float* W_query  = (const float*)d_in[12];
  const float* b_query  = (const float*)d_in[13];
  const float* W_out    = (const float*)d_in[14];
  const float* b_out    = (const float*)d_in[15];
  float* out = (float*)d_out;

  float* rep = (float*)d_ws;
  float* pf = rep + 524288;
  float* ph = pf + 524288;
  float* pq = ph + 524288;
  float* po = pq + 524288;
  u16* panels = (u16*)(po + 524288);

  hipMemcpyAsync(out + 524288, adj, 131072 * sizeof(float),
                 hipMemcpyDeviceToDevice, stream);

  C12 ca;
  ca.src[0]  = W_forget;             // F1  (rows 0:256   <- query_res)
  ca.src[1]  = W_forget + 256 * 256; // F2  (rows 256:512 <- hidden)
  ca.src[2]  = W_forget + 768 * 256; // F4  (rows 768:1024<- query)
  ca.src[3]  = W_hid;                // H1
  ca.src[4]  = W_hid + 256 * 256;    // H2  (<- forget*hidden)
  ca.src[5]  = W_hid + 768 * 256;    // H4
  ca.src[6]  = W_query;              // Q1  (rows 0:256 <- hidden)
  ca.src[7]  = W_query + 512 * 256;  // Q3  (rows 512:768 <- query)
  ca.src[8]  = W_out;                // O1
  ca.src[9]  = W_out + 512 * 256;    // O3
  ca.src[10] = W_srep;               // SR
  ca.src[11] = W_skey;               // SK
  cvt_panels<<<dim3(256, 12), 256, 0, stream>>>(ca, panels);

  G4 g1;
  for (int j = 0; j < 4; ++j) { g1.Bm[j] = W_self; g1.bias[j] = b_self; g1.C[j] = rep; }
  gemm16<<<dim3(128, 1), 256, 0, stream>>>(nodes, g1);

  G4 g2;
  g2.Bm[0] = W_forget + 512 * 256; g2.bias[0] = b_forget; g2.C[0] = pf;
  g2.Bm[1] = W_hid + 512 * 256;    g2.bias[1] = b_hid;    g2.C[1] = ph;
  g2.Bm[2] = W_query + 256 * 256;  g2.bias[2] = b_query;  g2.C[2] = pq;
  g2.Bm[3] = W_out + 256 * 256;    g2.bias[3] = b_out;    g2.C[3] = po;
  gemm16<<<dim3(128, 4), 256, 0, stream>>>(rep, g2);

  dagsage_main<<<16, 512, 0, stream>>>(adj, b_srep, b_skey,
                                       pf, ph, pq, po, panels, out);
}